// Round 1
// baseline (235.556 us; speedup 1.0000x reference)
//
#include <hip/hip_runtime.h>
#include <math.h>

// Problem dims (fixed by the reference)
#define SEQ   512
#define BATCH 1024
#define NFEAT 128
#define HID   20
#define NCLS  10

// ---------------------------------------------------------------------------
// Kernel A: xp[t][b][h] = dot(x[t][b][:], W_ih[h][:]) + b_ih[h] + b_hh[h]
// One thread per (t,b) row. x row read as 32x float4; W_ih indices are
// wave-uniform -> compiler emits scalar s_loads (no LDS needed).
// Memory-bound: 268 MB read + 42 MB write.
// ---------------------------------------------------------------------------
__global__ __launch_bounds__(256) void k_input_proj(
    const float* __restrict__ x, const float* __restrict__ W_ih,
    const float* __restrict__ b_ih, const float* __restrict__ b_hh,
    float* __restrict__ xp)
{
  const int row = blockIdx.x * blockDim.x + threadIdx.x;  // [0, SEQ*BATCH)
  const float4* __restrict__ xr =
      reinterpret_cast<const float4*>(x) + (size_t)row * (NFEAT / 4);

  float acc[HID];
#pragma unroll
  for (int h = 0; h < HID; ++h) acc[h] = 0.0f;

#pragma unroll 4
  for (int c = 0; c < NFEAT / 4; ++c) {
    const float4 xv = xr[c];
#pragma unroll
    for (int h = 0; h < HID; ++h) {
      const float4 wv = *reinterpret_cast<const float4*>(W_ih + h * NFEAT + c * 4);
      float a = acc[h];
      a = fmaf(xv.x, wv.x, a);
      a = fmaf(xv.y, wv.y, a);
      a = fmaf(xv.z, wv.z, a);
      a = fmaf(xv.w, wv.w, a);
      acc[h] = a;
    }
  }

  float* __restrict__ op = xp + (size_t)row * HID;
#pragma unroll
  for (int h = 0; h < HID; h += 4) {
    float4 o;
    o.x = acc[h + 0] + b_ih[h + 0] + b_hh[h + 0];
    o.y = acc[h + 1] + b_ih[h + 1] + b_hh[h + 1];
    o.z = acc[h + 2] + b_ih[h + 2] + b_hh[h + 2];
    o.w = acc[h + 3] + b_ih[h + 3] + b_hh[h + 3];
    *reinterpret_cast<float4*>(op + h) = o;
  }
}

// ---------------------------------------------------------------------------
// Kernel B: 512-step recurrence + final FC.
// 1 wave per block; 3 batches per wave, 20 lanes per batch (lane j owns h[j]
// and W_hh row j in VGPRs). h exchanged through LDS each step:
//   - single-wave block => lockstep + in-order DS pipe => NO s_barrier needed,
//     so the global xp prefetch stays in flight across steps (no vmcnt drain).
//   - 5x ds_read_b128 per step, bank-conflict-free (checked: group offsets
//     g*20 words mod 32 banks never collide for any 16B quad).
// xp loads double-buffered 8 steps ahead in registers (pure reg prefetch).
// ---------------------------------------------------------------------------
#define BPW 3   // batches per wave
#define PF  8   // prefetch chunk (steps)

__global__ __launch_bounds__(64) void k_rnn_scan(
    const float* __restrict__ xp, const float* __restrict__ W_hh,
    const float* __restrict__ W_fc, const float* __restrict__ b_fc,
    float* __restrict__ out)
{
  __shared__ __align__(16) float hsh[4][HID];  // [group][h], row 3 = lanes 60..63 scratch
  const int lane = threadIdx.x;
  const int g = lane / HID;        // 0..3
  const int j = lane - g * HID;    // 0..19
  const int b = blockIdx.x * BPW + g;
  const bool valid = (g < BPW) && (b < BATCH);
  const int beff = valid ? b : 0;  // safe load index for inactive lanes

  // W_hh row j -> registers (per-lane vector loads, done once)
  float w[HID];
  {
    const float4* wr = reinterpret_cast<const float4*>(W_hh + j * HID);
#pragma unroll
    for (int q = 0; q < HID / 4; ++q) {
      float4 v = wr[q];
      w[q * 4 + 0] = v.x; w[q * 4 + 1] = v.y;
      w[q * 4 + 2] = v.z; w[q * 4 + 3] = v.w;
    }
  }

  hsh[g][j] = 0.0f;                       // h0 = 0
  __builtin_amdgcn_wave_barrier();

  const float* __restrict__ xl = xp + beff * HID + j;
  const int STRIDE = BATCH * HID;         // elements per timestep
  const float4* __restrict__ hp = reinterpret_cast<const float4*>(&hsh[g][0]);

  float bufA[PF], bufB[PF];

#define STEPF(XV)                                                              \
  {                                                                            \
    float4 h0 = hp[0], h1 = hp[1], h2 = hp[2], h3 = hp[3], h4 = hp[4];         \
    float a0 = fmaf(w[3], h0.w, fmaf(w[2], h0.z, fmaf(w[1], h0.y, fmaf(w[0], h0.x, (XV))))); \
    float a1 = fmaf(w[7], h1.w, fmaf(w[6], h1.z, fmaf(w[5], h1.y, w[4] * h1.x)));            \
    float a2 = fmaf(w[11], h2.w, fmaf(w[10], h2.z, fmaf(w[9], h2.y, w[8] * h2.x)));          \
    float a3 = fmaf(w[15], h3.w, fmaf(w[14], h3.z, fmaf(w[13], h3.y, w[12] * h3.x)));        \
    float a4 = fmaf(w[19], h4.w, fmaf(w[18], h4.z, fmaf(w[17], h4.y, w[16] * h4.x)));        \
    float s = (a0 + a1) + ((a2 + a3) + a4);                                    \
    float hn = tanhf(s);                                                       \
    __builtin_amdgcn_wave_barrier();                                           \
    hsh[g][j] = hn;                                                            \
    __builtin_amdgcn_wave_barrier();                                           \
  }

  // prologue: preload chunk 0
#pragma unroll
  for (int i = 0; i < PF; ++i) bufA[i] = xl[(0 * PF + i) * STRIDE];

  for (int c = 0; c < SEQ / PF; c += 2) {
#pragma unroll
    for (int i = 0; i < PF; ++i) bufB[i] = xl[((c + 1) * PF + i) * STRIDE];
#pragma unroll
    for (int i = 0; i < PF; ++i) STEPF(bufA[i]);
    if (c + 2 < SEQ / PF) {
#pragma unroll
      for (int i = 0; i < PF; ++i) bufA[i] = xl[((c + 2) * PF + i) * STRIDE];
    }
#pragma unroll
    for (int i = 0; i < PF; ++i) STEPF(bufB[i]);
  }

  // epilogue: out[b][c] = b_fc[c] + sum_k W_fc[c][k] * h_final[k]
  if (valid && j < NCLS) {
    float acc = b_fc[j];
#pragma unroll
    for (int k = 0; k < HID; ++k)
      acc = fmaf(W_fc[j * HID + k], hsh[g][k], acc);
    out[b * NCLS + j] = acc;
  }
#undef STEPF
}

// ---------------------------------------------------------------------------
extern "C" void kernel_launch(void* const* d_in, const int* in_sizes, int n_in,
                              void* d_out, int out_size, void* d_ws, size_t ws_size,
                              hipStream_t stream) {
  const float* x    = (const float*)d_in[0];
  const float* W_ih = (const float*)d_in[1];
  const float* W_hh = (const float*)d_in[2];
  const float* b_ih = (const float*)d_in[3];
  const float* b_hh = (const float*)d_in[4];
  const float* W_fc = (const float*)d_in[5];
  const float* b_fc = (const float*)d_in[6];
  float* out = (float*)d_out;

  // xp scratch: SEQ*BATCH*HID floats = 41,943,040 bytes (must fit in d_ws)
  float* xp = (float*)d_ws;

  k_input_proj<<<(SEQ * BATCH) / 256, 256, 0, stream>>>(x, W_ih, b_ih, b_hh, xp);

  const int nblk = (BATCH + BPW - 1) / BPW;  // 342
  k_rnn_scan<<<nblk, 64, 0, stream>>>(xp, W_hh, W_fc, b_fc, out);
}